// Round 1
// baseline (786.563 us; speedup 1.0000x reference)
//
#include <hip/hip_runtime.h>
#include <hip/hip_bf16.h>
#include <math.h>

#define H_ 1024
#define D_ 2752
#define E_ 8
#define T_ 4096
#define MMAX_ 13312   /* max padded rows: 8 segs 128-aligned + 4096 shared */
#define MTILES_ 104

typedef __attribute__((ext_vector_type(8))) short s16x8;   // 8 bf16 in 4 VGPRs
typedef __attribute__((ext_vector_type(4))) float f32x4;

// async global->LDS, 16B per lane, LDS dest = wave-uniform base + lane*16
typedef __attribute__((address_space(3))) unsigned int lds_u32;
typedef const __attribute__((address_space(1))) unsigned int gbl_u32;
__device__ __forceinline__ void gload_lds16(const void* g, void* l) {
    __builtin_amdgcn_global_load_lds((gbl_u32*)g, (lds_u32*)l, 16, 0, 0);
}

__device__ __forceinline__ float bf2f(short us) {
    unsigned int u = ((unsigned int)(unsigned short)us) << 16;
    return __uint_as_float(u);
}

// ---------------- init: zero counters / row metadata ----------------
__global__ void k_init(int* __restrict__ count, int* __restrict__ perm,
                       float* __restrict__ wrow) {
    int i = blockIdx.x * 256 + threadIdx.x;
    if (i < E_) count[i] = 0;
    if (i < MMAX_) { perm[i] = 0; wrow[i] = 0.f; }
}

// ---------------- gate: fp32-exact logits, top-2, renormed weights ----------------
__global__ void k_gate(const float* __restrict__ x, const float* __restrict__ gw,
                       int* __restrict__ topk_e, float* __restrict__ topk_w,
                       int* __restrict__ count) {
    int t = blockIdx.x;
    int lane = threadIdx.x;   // 64 threads
    const float* xrow = x + (size_t)t * H_;
    float xr[16];
#pragma unroll
    for (int i = 0; i < 16; ++i) xr[i] = xrow[lane + i * 64];
    float lg[E_];
#pragma unroll
    for (int e = 0; e < E_; ++e) {
        const float* g = gw + (size_t)e * H_;
        float s = 0.f;
#pragma unroll
        for (int i = 0; i < 16; ++i) s += xr[i] * g[lane + i * 64];
        for (int o = 32; o > 0; o >>= 1) s += __shfl_down(s, o, 64);
        lg[e] = s;   // valid on lane 0
    }
    if (lane == 0) {
        int e0 = 0; float l0 = lg[0];
#pragma unroll
        for (int e = 1; e < E_; ++e) if (lg[e] > l0) { l0 = lg[e]; e0 = e; }
        int e1 = -1; float l1 = -1e30f;
#pragma unroll
        for (int e = 0; e < E_; ++e) if (e != e0 && lg[e] > l1) { l1 = lg[e]; e1 = e; }
        float w0 = 1.f / (1.f + expf(l1 - l0));   // softmax denom cancels in renorm
        float w1 = 1.f - w0;
        topk_e[2 * t] = e0; topk_e[2 * t + 1] = e1;
        topk_w[2 * t] = w0; topk_w[2 * t + 1] = w1;
        atomicAdd(&count[e0], 1);
        atomicAdd(&count[e1], 1);
    }
}

// ---------------- scan: 128-aligned segment offsets ----------------
__global__ void k_scan(const int* __restrict__ count, int* __restrict__ off,
                       int* __restrict__ count2) {
    if (threadIdx.x == 0) {
        int o = 0; off[0] = 0;
        for (int e = 0; e < E_; ++e) { o += (count[e] + 127) & ~127; off[e + 1] = o; }
    }
    if (threadIdx.x < E_) count2[threadIdx.x] = 0;
}

// ---------------- scatter: token -> row; also record token's row ids ----------------
__global__ void k_scatter(const int* __restrict__ topk_e, const float* __restrict__ topk_w,
                          const int* __restrict__ off, int* __restrict__ count2,
                          int* __restrict__ perm, float* __restrict__ wrow,
                          int* __restrict__ tok2row) {
    int i = blockIdx.x * 256 + threadIdx.x;
    if (i < 2 * T_) {
        int e = topk_e[i];
        int pos = atomicAdd(&count2[e], 1);
        int r = off[e] + pos;
        perm[r] = i >> 1;
        wrow[r] = topk_w[i];
        tok2row[i] = r;
    } else if (i < 3 * T_) {
        int t = i - 2 * T_;
        int r = off[E_] + t;     // shared-expert segment
        perm[r] = t;
        wrow[r] = 1.f;
    }
}

// ---------------- gather: build Xg rows (bf16), zeros for pad rows ----------------
__global__ void k_gather(const float* __restrict__ x, const int* __restrict__ perm,
                         const float* __restrict__ wrow, __hip_bfloat16* __restrict__ Xg) {
    int r = blockIdx.x;
    int j = threadIdx.x;              // 128 threads, 8 elems each
    int t = perm[r];
    bool act = (wrow[r] != 0.f);
    const float* src = x + (size_t)t * H_;
    __hip_bfloat16* dst = Xg + (size_t)r * H_;
    int h = j * 8;
    float v[8];
#pragma unroll
    for (int i = 0; i < 8; ++i) v[i] = 0.f;
    if (act) {
        float4 a = *(const float4*)(src + h);
        float4 b = *(const float4*)(src + h + 4);
        v[0] = a.x; v[1] = a.y; v[2] = a.z; v[3] = a.w;
        v[4] = b.x; v[5] = b.y; v[6] = b.z; v[7] = b.w;
    }
    __hip_bfloat16 tmp[8];
#pragma unroll
    for (int i = 0; i < 8; ++i) tmp[i] = __float2bfloat16(v[i]);
    *(s16x8*)(dst + h) = *(const s16x8*)tmp;
}

// ---------------- transpose+convert: fp32 [R][C] -> bf16 [C][R], 64x64 tiles ----------------
__global__ void k_transpose(const float* __restrict__ src_, __hip_bfloat16* __restrict__ dst_,
                            int R, int C) {
    const float* src = src_ + (size_t)blockIdx.z * R * C;
    __hip_bfloat16* dst = dst_ + (size_t)blockIdx.z * R * C;
    __shared__ __hip_bfloat16 tile[64][68];   // 68: 8B-aligned rows, conflict break
    int c0 = blockIdx.x * 64, r0 = blockIdx.y * 64;
    int tid = threadIdx.x;                     // 256
    int rsub = tid >> 4;                       // 0..15
    int csub = (tid & 15) * 4;                 // 0..60
#pragma unroll
    for (int i = 0; i < 4; ++i) {
        int r = rsub + i * 16;
        float4 v = *(const float4*)(src + (size_t)(r0 + r) * C + c0 + csub);
        tile[csub + 0][r] = __float2bfloat16(v.x);
        tile[csub + 1][r] = __float2bfloat16(v.y);
        tile[csub + 2][r] = __float2bfloat16(v.z);
        tile[csub + 3][r] = __float2bfloat16(v.w);
    }
    __syncthreads();
    int cs2 = tid >> 4;
    int rs2 = (tid & 15) * 4;
#pragma unroll
    for (int i = 0; i < 4; ++i) {
        int cc = cs2 + i * 16;
        short4 o = *(const short4*)&tile[cc][rs2];
        *(short4*)((unsigned short*)dst + (size_t)(c0 + cc) * R + r0 + rs2) = o;
    }
}

// Bank-swizzle: chunk (tile-row R, k-chunk q of 8 bf16) lives at ushort offset
// R*32 + ((q + (R>>1)) & 3) * 8 within its staging buffer. Staging lane l of
// issue s holds slot l&3 of row s*16 + (l>>2)  ->  global chunk
// c = ((l&3) - (row>>1)) & 3. 8 consecutive lanes of a ds_read_b128 then
// cover all 8 bank-quads (conflict-free).

// ---------------- GEMM1: hidden = silu(Xg*WgT^T) * (Xg*WuT^T), bf16 out ----------------
__global__ __launch_bounds__(256, 2) void k_gemm1(
    const unsigned short* __restrict__ Xg,
    const unsigned short* __restrict__ WgT,
    const unsigned short* __restrict__ WuT,
    __hip_bfloat16* __restrict__ hidden,
    const int* __restrict__ off) {
    __shared__ unsigned short lds[2][3][4096];   // 2 sets x {A,Bg,Bu} x 8KB

    int row0 = blockIdx.y * 128;
    int off9[9];
#pragma unroll
    for (int i = 0; i < 9; ++i) off9[i] = off[i];
    int Mtot = off9[8] + T_;                 // 128-aligned
    if (row0 >= Mtot) return;
    int e = 0;
#pragma unroll
    for (int i = 1; i < 9; ++i) e += (row0 >= off9[i]) ? 1 : 0;

    int n0 = blockIdx.x * 128;
    size_t wbase = (size_t)e * D_ * H_;
    const unsigned short* Bg = WgT + wbase;
    const unsigned short* Bu = WuT + wbase;

    int tid = threadIdx.x;
    int wave = tid >> 6, lane = tid & 63;
    int wm = wave >> 1, wn = wave & 1;
    int ml = lane & 15, q = lane >> 4;
    int sw = ((q + (ml >> 1)) & 3) * 8;     // read-side swizzle (uniform in i/j)

    f32x4 accg[4][4], accu[4][4];
#pragma unroll
    for (int i = 0; i < 4; ++i)
#pragma unroll
        for (int j = 0; j < 4; ++j) { accg[i][j] = (f32x4)0.f; accu[i][j] = (f32x4)0.f; }

    // 24 direct-to-LDS issues per k-step (3 bufs x 8), 6 per wave
    const unsigned short* gsrc[6];
    unsigned short* lbase[6];
#pragma unroll
    for (int i = 0; i < 6; ++i) {
        int qq = wave * 6 + i;
        int buf = qq >> 3, s = qq & 7;
        int r = s * 16 + (lane >> 2);                    // tile-local row
        int c = ((lane & 3) - (r >> 1)) & 3;             // swizzled k-chunk
        lbase[i] = &lds[0][buf][s * 512];
        const unsigned short* g;
        if (buf == 0) {
            g = Xg + (size_t)(row0 + r) * H_ + c * 8;
        } else {
            int bn = n0 + r; if (bn > D_ - 1) bn = D_ - 1;   // dup tail, masked in epilogue
            g = (buf == 1 ? Bg : Bu) + (size_t)bn * H_ + c * 8;
        }
        gsrc[i] = g;
    }

    auto issue = [&](int k0, int set) {
#pragma unroll
        for (int i = 0; i < 6; ++i)
            gload_lds16(gsrc[i] + k0, lbase[i] + set * 12288);
    };
    auto compute = [&](int set) {
        const unsigned short* S = &lds[set][0][0];
        s16x8 af[4], bgf[4], buf2[4];
#pragma unroll
        for (int i = 0; i < 4; ++i) {
            int R = wm * 64 + i * 16 + ml;
            af[i] = *(const s16x8*)(S + R * 32 + sw);
        }
#pragma unroll
        for (int j = 0; j < 4; ++j) {
            int R = wn * 64 + j * 16 + ml;
            int o2 = R * 32 + sw;
            bgf[j]  = *(const s16x8*)(S + 4096 + o2);
            buf2[j] = *(const s16x8*)(S + 8192 + o2);
        }
#pragma unroll
        for (int i = 0; i < 4; ++i)
#pragma unroll
            for (int j = 0; j < 4; ++j) {
                accg[i][j] = __builtin_amdgcn_mfma_f32_16x16x32_bf16(af[i], bgf[j],  accg[i][j], 0, 0, 0);
                accu[i][j] = __builtin_amdgcn_mfma_f32_16x16x32_bf16(af[i], buf2[j], accu[i][j], 0, 0, 0);
            }
    };

    // single-barrier ping-pong: loads for step k+1 fly during step k's compute
    issue(0, 0);
    for (int k0 = 0; k0 < H_; k0 += 64) {
        __syncthreads();               // drains set-0 loads; set-1 reads of prev iter done
        issue(k0 + 32, 1);
        compute(0);
        __syncthreads();               // drains set-1 loads
        if (k0 + 64 < H_) issue(k0 + 64, 0);
        compute(1);
    }

    // epilogue: C/D layout col=lane&15, row=(lane>>4)*4+reg  [m89/m91]
    int mbase = row0 + wm * 64;
    int nbase = n0 + wn * 64;
#pragma unroll
    for (int i = 0; i < 4; ++i)
#pragma unroll
        for (int j = 0; j < 4; ++j) {
            int n = nbase + j * 16 + ml;
            if (n < D_) {
#pragma unroll
                for (int r = 0; r < 4; ++r) {
                    int m = mbase + i * 16 + q * 4 + r;
                    float g = accg[i][j][r], u = accu[i][j][r];
                    float hv = (g / (1.f + __expf(-g))) * u;   // silu(g)*u
                    hidden[(size_t)m * D_ + n] = __float2bfloat16(hv);
                }
            }
        }
}

// ---------------- GEMM2: eo[r] = hidden[r] * WdT^T  (bf16 out, unweighted) ----------------
__global__ __launch_bounds__(256, 2) void k_gemm2(
    const unsigned short* __restrict__ Hd,
    const unsigned short* __restrict__ WdT,
    const int* __restrict__ off,
    __hip_bfloat16* __restrict__ eo) {
    __shared__ unsigned short lds[2][2][4096];   // 2 sets x {A,B} x 8KB

    int row0 = blockIdx.y * 128;
    int off9[9];
#pragma unroll
    for (int i = 0; i < 9; ++i) off9[i] = off[i];
    int Mtot = off9[8] + T_;
    if (row0 >= Mtot) return;
    int e = 0;
#pragma unroll
    for (int i = 1; i < 9; ++i) e += (row0 >= off9[i]) ? 1 : 0;

    int n0 = blockIdx.x * 128;                      // N=1024, exact
    const unsigned short* Bd = WdT + (size_t)e * H_ * D_;

    int tid = threadIdx.x;
    int wave = tid >> 6, lane = tid & 63;
    int wm = wave >> 1, wn = wave & 1;
    int ml = lane & 15, q = lane >> 4;
    int sw = ((q + (ml >> 1)) & 3) * 8;

    f32x4 acc[4][4];
#pragma unroll
    for (int i = 0; i < 4; ++i)
#pragma unroll
        for (int j = 0; j < 4; ++j) acc[i][j] = (f32x4)0.f;

    const unsigned short* gsrc[4];
    unsigned short* lbase[4];
#pragma unroll
    for (int i = 0; i < 4; ++i) {
        int qq = wave * 4 + i;
        int buf = qq >> 3, s = qq & 7;
        int r = s * 16 + (lane >> 2);
        int c = ((lane & 3) - (r >> 1)) & 3;
        lbase[i] = &lds[0][buf][s * 512];
        gsrc[i] = (buf == 0)
            ? Hd + (size_t)(row0 + r) * D_ + c * 8
            : Bd + (size_t)(n0 + r) * D_ + c * 8;
    }

    auto issue = [&](int k0, int set) {
#pragma unroll
        for (int i = 0; i < 4; ++i)
            gload_lds16(gsrc[i] + k0, lbase[i] + set * 8192);
    };
    auto compute = [&](int set) {
        const unsigned short* S = &lds[set][0][0];
        s16x8 af[4], bf[4];
#pragma unroll
        for (int i = 0; i < 4; ++i) {
            int R = wm * 64 + i * 16 + ml;
            af[i] = *(const s16x8*)(S + R * 32 + sw);
        }
#pragma unroll
        for (int j = 0; j < 4; ++j) {
            int R = wn * 64 + j * 16 + ml;
            bf[j] = *(const s16x8*)(S + 4096 + R * 32 + sw);
        }
#pragma unroll
        for (int i = 0; i < 4; ++i)
#pragma unroll
            for (int j = 0; j < 4; ++j)
                acc[i][j] = __builtin_amdgcn_mfma_f32_16x16x32_bf16(af[i], bf[j], acc[i][j], 0, 0, 0);
    };

    issue(0, 0);
    for (int k0 = 0; k0 < D_; k0 += 64) {           // D_=2752 = 43*64
        __syncthreads();
        issue(k0 + 32, 1);
        compute(0);
        __syncthreads();
        if (k0 + 64 < D_) issue(k0 + 64, 0);
        compute(1);
    }

    int mbase = row0 + wm * 64;
    int nbase = n0 + wn * 64;
#pragma unroll
    for (int i = 0; i < 4; ++i)
#pragma unroll
        for (int r = 0; r < 4; ++r) {
            int m = mbase + i * 16 + q * 4 + r;
#pragma unroll
            for (int j = 0; j < 4; ++j) {
                int n = nbase + j * 16 + ml;
                eo[(size_t)m * H_ + n] = __float2bfloat16(acc[i][j][r]);
            }
        }
}

// ---------------- combine: out[t] = w0*eo[r0] + w1*eo[r1] + eo[rshared] ----------------
__global__ void k_combine(const unsigned short* __restrict__ eo, const int* __restrict__ tok2row,
                          const int* __restrict__ off, const float* __restrict__ topk_w,
                          float* __restrict__ out) {
    int t = blockIdx.x;
    int j = threadIdx.x * 8;                  // H = 128*8
    int r0 = tok2row[2 * t], r1 = tok2row[2 * t + 1];
    int rs = off[E_] + t;
    float w0 = topk_w[2 * t], w1 = topk_w[2 * t + 1];
    s16x8 a = *(const s16x8*)(eo + (size_t)r0 * H_ + j);
    s16x8 b = *(const s16x8*)(eo + (size_t)r1 * H_ + j);
    s16x8 c = *(const s16x8*)(eo + (size_t)rs * H_ + j);
    float o[8];
#pragma unroll
    for (int i = 0; i < 8; ++i)
        o[i] = w0 * bf2f(a[i]) + w1 * bf2f(b[i]) + bf2f(c[i]);
    float* dst = out + (size_t)t * H_ + j;
    *(float4*)(dst)     = make_float4(o[0], o[1], o[2], o[3]);
    *(float4*)(dst + 4) = make_float4(o[4], o[5], o[6], o[7]);
}

// ---------------- launch ----------------
extern "C" void kernel_launch(void* const* d_in, const int* in_sizes, int n_in,
                              void* d_out, int out_size, void* d_ws, size_t ws_size,
                              hipStream_t stream) {
    const float* x       = (const float*)d_in[0];
    const float* gw      = (const float*)d_in[1];
    const float* we_gate = (const float*)d_in[2];
    const float* we_up   = (const float*)d_in[3];
    const float* we_down = (const float*)d_in[4];
    const float* sw_gate = (const float*)d_in[5];
    const float* sw_up   = (const float*)d_in[6];
    const float* sw_down = (const float*)d_in[7];

    char* ws = (char*)d_ws;
    size_t o = 0;
    auto alloc = [&](size_t b) -> void* {
        void* p = ws + o;
        o += (b + 255) & ~(size_t)255;
        return p;
    };
    int*   count   = (int*)alloc(E_ * 4);
    int*   count2  = (int*)alloc(E_ * 4);
    int*   off     = (int*)alloc(16 * 4);
    int*   topk_e  = (int*)alloc(2 * T_ * 4);
    float* topk_w  = (float*)alloc(2 * T_ * 4);
    int*   perm    = (int*)alloc(MMAX_ * 4);
    float* wrow    = (float*)alloc(MMAX_ * 4);
    int*   tok2row = (int*)alloc(2 * T_ * 4);
    __hip_bfloat16* Xg  = (__hip_bfloat16*)alloc((size_t)MMAX_ * H_ * 2);
    __hip_bfloat16* WgT = (__hip_bfloat16*)alloc((size_t)(E_ + 1) * D_ * H_ * 2);
    __hip_bfloat16* WuT = (__hip_bfloat16*)alloc((size_t)(E_ + 1) * D_ * H_ * 2);
    __hip_bfloat16* WdT = (__hip_bfloat16*)alloc((size_t)(E_ + 1) * H_ * D_ * 2);
    __hip_bfloat16* hidden = (__hip_bfloat16*)alloc((size_t)MMAX_ * D_ * 2);
    // eo (bf16, 27 MB) aliases WgT (50 MB), dead after GEMM1
    __hip_bfloat16* eo = WgT;

    // routing
    k_init<<<(MMAX_ + 255) / 256, 256, 0, stream>>>(count, perm, wrow);
    k_gate<<<T_, 64, 0, stream>>>(x, gw, topk_e, topk_w, count);
    k_scan<<<1, 64, 0, stream>>>(count, off, count2);
    k_scatter<<<(3 * T_ + 255) / 256, 256, 0, stream>>>(topk_e, topk_w, off, count2,
                                                        perm, wrow, tok2row);
    k_gather<<<MMAX_, 128, 0, stream>>>(x, perm, wrow, Xg);

    // weight transpose+convert: experts in slots 0..7, shared in slot 8
    size_t msz = (size_t)D_ * H_;
    k_transpose<<<dim3(D_ / 64, H_ / 64, E_), 256, 0, stream>>>(we_gate, WgT, H_, D_);
    k_transpose<<<dim3(D_ / 64, H_ / 64, 1), 256, 0, stream>>>(sw_gate, WgT + E_ * msz, H_, D_);
    k_transpose<<<dim3(D_ / 64, H_ / 64, E_), 256, 0, stream>>>(we_up, WuT, H_, D_);
    k_transpose<<<dim3(D_ / 64, H_ / 64, 1), 256, 0, stream>>>(sw_up, WuT + E_ * msz, H_, D_);
    k_transpose<<<dim3(H_ / 64, D_ / 64, E_), 256, 0, stream>>>(we_down, WdT, D_, H_);
    k_transpose<<<dim3(H_ / 64, D_ / 64, 1), 256, 0, stream>>>(sw_down, WdT + E_ * msz, D_, H_);

    // GEMM1: fused gate+up+silu -> hidden (bf16)
    k_gemm1<<<dim3((D_ + 127) / 128, MTILES_), 256, 0, stream>>>(
        (const unsigned short*)Xg, (const unsigned short*)WgT, (const unsigned short*)WuT,
        hidden, off);

    // GEMM2: down-proj -> eo rows (bf16, unweighted)
    k_gemm2<<<dim3(H_ / 128, MTILES_), 256, 0, stream>>>(
        (const unsigned short*)hidden, (const unsigned short*)WdT, off, eo);

    // combine: weighted sum of the token's 3 rows
    k_combine<<<T_, 128, 0, stream>>>((const unsigned short*)eo, tok2row, off, topk_w,
                                      (float*)d_out);
}

// Round 2
// 783.871 us; speedup vs baseline: 1.0034x; 1.0034x over previous
//
#include <hip/hip_runtime.h>
#include <hip/hip_bf16.h>
#include <math.h>

#define H_ 1024
#define D_ 2752
#define E_ 8
#define T_ 4096
#define MMAX_ 14336   /* max padded rows: 8 segs 256-aligned + 4096 shared */
#define MT256_ 56     /* GEMM1 m-tiles (BM=256) */
#define MT128_ 112    /* GEMM2 m-tiles (BM=128) */

typedef __attribute__((ext_vector_type(8))) short s16x8;   // 8 bf16 in 4 VGPRs
typedef __attribute__((ext_vector_type(4))) float f32x4;

// async global->LDS, 16B per lane, LDS dest = wave-uniform base + lane*16
typedef __attribute__((address_space(3))) unsigned int lds_u32;
typedef const __attribute__((address_space(1))) unsigned int gbl_u32;
__device__ __forceinline__ void gload_lds16(const void* g, void* l) {
    __builtin_amdgcn_global_load_lds((gbl_u32*)g, (lds_u32*)l, 16, 0, 0);
}

__device__ __forceinline__ float bf2f(short us) {
    unsigned int u = ((unsigned int)(unsigned short)us) << 16;
    return __uint_as_float(u);
}

// ---------------- init: zero counters / row metadata ----------------
__global__ void k_init(int* __restrict__ count, int* __restrict__ perm,
                       float* __restrict__ wrow) {
    int i = blockIdx.x * 256 + threadIdx.x;
    if (i < E_) count[i] = 0;
    if (i < MMAX_) { perm[i] = 0; wrow[i] = 0.f; }
}

// ---------------- gate: fp32-exact logits, top-2, renormed weights ----------------
__global__ void k_gate(const float* __restrict__ x, const float* __restrict__ gw,
                       int* __restrict__ topk_e, float* __restrict__ topk_w,
                       int* __restrict__ count) {
    int t = blockIdx.x;
    int lane = threadIdx.x;   // 64 threads
    const float* xrow = x + (size_t)t * H_;
    float xr[16];
#pragma unroll
    for (int i = 0; i < 16; ++i) xr[i] = xrow[lane + i * 64];
    float lg[E_];
#pragma unroll
    for (int e = 0; e < E_; ++e) {
        const float* g = gw + (size_t)e * H_;
        float s = 0.f;
#pragma unroll
        for (int i = 0; i < 16; ++i) s += xr[i] * g[lane + i * 64];
        for (int o = 32; o > 0; o >>= 1) s += __shfl_down(s, o, 64);
        lg[e] = s;   // valid on lane 0
    }
    if (lane == 0) {
        int e0 = 0; float l0 = lg[0];
#pragma unroll
        for (int e = 1; e < E_; ++e) if (lg[e] > l0) { l0 = lg[e]; e0 = e; }
        int e1 = -1; float l1 = -1e30f;
#pragma unroll
        for (int e = 0; e < E_; ++e) if (e != e0 && lg[e] > l1) { l1 = lg[e]; e1 = e; }
        float w0 = 1.f / (1.f + expf(l1 - l0));   // softmax denom cancels in renorm
        float w1 = 1.f - w0;
        topk_e[2 * t] = e0; topk_e[2 * t + 1] = e1;
        topk_w[2 * t] = w0; topk_w[2 * t + 1] = w1;
        atomicAdd(&count[e0], 1);
        atomicAdd(&count[e1], 1);
    }
}

// ---------------- scan: 256-aligned segment offsets ----------------
__global__ void k_scan(const int* __restrict__ count, int* __restrict__ off,
                       int* __restrict__ count2) {
    if (threadIdx.x == 0) {
        int o = 0; off[0] = 0;
        for (int e = 0; e < E_; ++e) { o += (count[e] + 255) & ~255; off[e + 1] = o; }
    }
    if (threadIdx.x < E_) count2[threadIdx.x] = 0;
}

// ---------------- scatter: token -> row; also record token's row ids ----------------
__global__ void k_scatter(const int* __restrict__ topk_e, const float* __restrict__ topk_w,
                          const int* __restrict__ off, int* __restrict__ count2,
                          int* __restrict__ perm, float* __restrict__ wrow,
                          int* __restrict__ tok2row) {
    int i = blockIdx.x * 256 + threadIdx.x;
    if (i < 2 * T_) {
        int e = topk_e[i];
        int pos = atomicAdd(&count2[e], 1);
        int r = off[e] + pos;
        perm[r] = i >> 1;
        wrow[r] = topk_w[i];
        tok2row[i] = r;
    } else if (i < 3 * T_) {
        int t = i - 2 * T_;
        int r = off[E_] + t;     // shared-expert segment
        perm[r] = t;
        wrow[r] = 1.f;
    }
}

// ---------------- gather: build Xg rows (bf16), zeros for pad rows ----------------
__global__ void k_gather(const float* __restrict__ x, const int* __restrict__ perm,
                         const float* __restrict__ wrow, __hip_bfloat16* __restrict__ Xg) {
    int r = blockIdx.x;
    int j = threadIdx.x;              // 128 threads, 8 elems each
    int t = perm[r];
    bool act = (wrow[r] != 0.f);
    const float* src = x + (size_t)t * H_;
    __hip_bfloat16* dst = Xg + (size_t)r * H_;
    int h = j * 8;
    float v[8];
#pragma unroll
    for (int i = 0; i < 8; ++i) v[i] = 0.f;
    if (act) {
        float4 a = *(const float4*)(src + h);
        float4 b = *(const float4*)(src + h + 4);
        v[0] = a.x; v[1] = a.y; v[2] = a.z; v[3] = a.w;
        v[4] = b.x; v[5] = b.y; v[6] = b.z; v[7] = b.w;
    }
    __hip_bfloat16 tmp[8];
#pragma unroll
    for (int i = 0; i < 8; ++i) tmp[i] = __float2bfloat16(v[i]);
    *(s16x8*)(dst + h) = *(const s16x8*)tmp;
}

// ---------------- transpose+convert: fp32 [R][C] -> bf16 [C][R], 64x64 tiles ----------------
__global__ void k_transpose(const float* __restrict__ src_, __hip_bfloat16* __restrict__ dst_,
                            int R, int C) {
    const float* src = src_ + (size_t)blockIdx.z * R * C;
    __hip_bfloat16* dst = dst_ + (size_t)blockIdx.z * R * C;
    __shared__ __hip_bfloat16 tile[64][68];   // 68: 8B-aligned rows, conflict break
    int c0 = blockIdx.x * 64, r0 = blockIdx.y * 64;
    int tid = threadIdx.x;                     // 256
    int rsub = tid >> 4;                       // 0..15
    int csub = (tid & 15) * 4;                 // 0..60
#pragma unroll
    for (int i = 0; i < 4; ++i) {
        int r = rsub + i * 16;
        float4 v = *(const float4*)(src + (size_t)(r0 + r) * C + c0 + csub);
        tile[csub + 0][r] = __float2bfloat16(v.x);
        tile[csub + 1][r] = __float2bfloat16(v.y);
        tile[csub + 2][r] = __float2bfloat16(v.z);
        tile[csub + 3][r] = __float2bfloat16(v.w);
    }
    __syncthreads();
    int cs2 = tid >> 4;
    int rs2 = (tid & 15) * 4;
#pragma unroll
    for (int i = 0; i < 4; ++i) {
        int cc = cs2 + i * 16;
        short4 o = *(const short4*)&tile[cc][rs2];
        *(short4*)((unsigned short*)dst + (size_t)(c0 + cc) * R + r0 + rs2) = o;
    }
}

// Bank-swizzle: chunk (tile-row R, k-chunk q of 8 bf16) lives at ushort offset
// R*32 + ((q + (R>>1)) & 3) * 8 within its staging buffer. Staging lane l of
// issue s holds slot l&3 of row s*16 + (l>>2)  ->  global chunk
// c = ((l&3) - (row>>1)) & 3. 8 consecutive lanes of a ds_read_b128 then
// cover all 8 bank-quads (conflict-free).

// ---------------- GEMM1: hidden = silu(Xg*WgT^T) * (Xg*WuT^T), bf16 out ----------------
// 512 thr (8 waves, 4m x 2n), BM=256 BN=128, 4 half-sets (BK=32) depth-3
// counted-vmcnt pipeline (T3+T4) + setprio (T5). 128 KiB LDS, 1 block/CU.
__global__ __launch_bounds__(512, 2) void k_gemm1(
    const unsigned short* __restrict__ Xg,
    const unsigned short* __restrict__ WgT,
    const unsigned short* __restrict__ WuT,
    __hip_bfloat16* __restrict__ hidden,
    const int* __restrict__ off) {
    __shared__ unsigned short lds[4][16384];   // 4 slots x {A 16KB, Bg 8KB, Bu 8KB}

    int row0 = blockIdx.y * 256;
    int off9[9];
#pragma unroll
    for (int i = 0; i < 9; ++i) off9[i] = off[i];
    int Mtot = off9[8] + T_;                 // 256-aligned
    if (row0 >= Mtot) return;
    int e = 0;
#pragma unroll
    for (int i = 1; i < 9; ++i) e += (row0 >= off9[i]) ? 1 : 0;

    int n0 = blockIdx.x * 128;
    size_t wbase = (size_t)e * D_ * H_;
    const unsigned short* Bg = WgT + wbase;
    const unsigned short* Bu = WuT + wbase;

    int tid = threadIdx.x;
    int wave = tid >> 6, lane = tid & 63;
    int wm = wave >> 1, wn = wave & 1;       // 4m x 2n, 64x64 per wave
    int ml = lane & 15, q = lane >> 4;
    int sw = ((q + (ml >> 1)) & 3) * 8;      // read-side swizzle

    f32x4 accg[4][4], accu[4][4];
#pragma unroll
    for (int i = 0; i < 4; ++i)
#pragma unroll
        for (int j = 0; j < 4; ++j) { accg[i][j] = (f32x4)0.f; accu[i][j] = (f32x4)0.f; }

    // 32 sub-issues per half-set (A:16, Bg:8, Bu:8), 4 per wave
    const unsigned short* gsrc[4];
    int loff[4];
#pragma unroll
    for (int i = 0; i < 4; ++i) {
        int qq = wave * 4 + i;
        int lr = lane >> 2;
        if (qq < 16) {                                     // A: rows 0..255
            int s = qq;
            int r = s * 16 + lr;
            int c = ((lane & 3) - (r >> 1)) & 3;
            loff[i] = s * 512;
            gsrc[i] = Xg + (size_t)(row0 + r) * H_ + c * 8;
        } else if (qq < 24) {                              // Bg: rows 0..127
            int s = qq - 16;
            int r = s * 16 + lr;
            int c = ((lane & 3) - (r >> 1)) & 3;
            int bn = n0 + r; if (bn > D_ - 1) bn = D_ - 1; // dup tail, masked later
            loff[i] = 8192 + s * 512;
            gsrc[i] = Bg + (size_t)bn * H_ + c * 8;
        } else {                                           // Bu: rows 0..127
            int s = qq - 24;
            int r = s * 16 + lr;
            int c = ((lane & 3) - (r >> 1)) & 3;
            int bn = n0 + r; if (bn > D_ - 1) bn = D_ - 1;
            loff[i] = 12288 + s * 512;
            gsrc[i] = Bu + (size_t)bn * H_ + c * 8;
        }
    }

    auto issue = [&](int hs) {
        unsigned short* base = &lds[hs & 3][0];
        int ko = hs * 32;
#pragma unroll
        for (int i = 0; i < 4; ++i)
            gload_lds16(gsrc[i] + ko, base + loff[i]);
    };
    auto compute = [&](int hs) {
        const unsigned short* S = &lds[hs & 3][0];
        s16x8 af[4], bgf[4], buf2[4];
#pragma unroll
        for (int i = 0; i < 4; ++i) {
            int R = wm * 64 + i * 16 + ml;
            af[i] = *(const s16x8*)(S + R * 32 + sw);
        }
#pragma unroll
        for (int j = 0; j < 4; ++j) {
            int R = wn * 64 + j * 16 + ml;
            int o2 = R * 32 + sw;
            bgf[j]  = *(const s16x8*)(S + 8192 + o2);
            buf2[j] = *(const s16x8*)(S + 12288 + o2);
        }
        __builtin_amdgcn_s_setprio(1);
#pragma unroll
        for (int i = 0; i < 4; ++i)
#pragma unroll
            for (int j = 0; j < 4; ++j) {
                accg[i][j] = __builtin_amdgcn_mfma_f32_16x16x32_bf16(af[i], bgf[j],  accg[i][j], 0, 0, 0);
                accu[i][j] = __builtin_amdgcn_mfma_f32_16x16x32_bf16(af[i], buf2[j], accu[i][j], 0, 0, 0);
            }
        __builtin_amdgcn_s_setprio(0);
    };

    // depth-3 pipeline: slots rotate mod 4; writing slot (hs+3)&3 after barrier hs
    // is safe because all waves completed compute(hs-1) (same slot) before it.
    const int NH = H_ / 32;   // 32 half-steps
    issue(0); issue(1); issue(2);             // 12 vmem ops outstanding
    for (int hs = 0; hs < NH - 2; ++hs) {
        asm volatile("s_waitcnt vmcnt(8)" ::: "memory");   // oldest 4 (set hs) landed
        __builtin_amdgcn_s_barrier();
        __builtin_amdgcn_sched_barrier(0);
        if (hs + 3 < NH) issue(hs + 3);
        compute(hs);
    }
    asm volatile("s_waitcnt vmcnt(4)" ::: "memory");
    __builtin_amdgcn_s_barrier();
    __builtin_amdgcn_sched_barrier(0);
    compute(NH - 2);
    asm volatile("s_waitcnt vmcnt(0)" ::: "memory");
    __builtin_amdgcn_s_barrier();
    __builtin_amdgcn_sched_barrier(0);
    compute(NH - 1);

    // epilogue: C/D layout col=lane&15, row=(lane>>4)*4+reg  [m89/m91]
    int mbase = row0 + wm * 64;
    int nbase = n0 + wn * 64;
#pragma unroll
    for (int i = 0; i < 4; ++i)
#pragma unroll
        for (int j = 0; j < 4; ++j) {
            int n = nbase + j * 16 + ml;
            if (n < D_) {
#pragma unroll
                for (int r = 0; r < 4; ++r) {
                    int m = mbase + i * 16 + q * 4 + r;
                    float g = accg[i][j][r], u = accu[i][j][r];
                    float hv = (g / (1.f + __expf(-g))) * u;   // silu(g)*u
                    hidden[(size_t)m * D_ + n] = __float2bfloat16(hv);
                }
            }
        }
}

// ---------------- GEMM2: eo[r] = hidden[r] * WdT^T  (bf16 out, unweighted) ----------------
__global__ __launch_bounds__(256, 2) void k_gemm2(
    const unsigned short* __restrict__ Hd,
    const unsigned short* __restrict__ WdT,
    const int* __restrict__ off,
    __hip_bfloat16* __restrict__ eo) {
    __shared__ unsigned short lds[2][2][4096];   // 2 sets x {A,B} x 8KB

    int row0 = blockIdx.y * 128;
    int off9[9];
#pragma unroll
    for (int i = 0; i < 9; ++i) off9[i] = off[i];
    int Mtot = off9[8] + T_;
    if (row0 >= Mtot) return;
    int e = 0;
#pragma unroll
    for (int i = 1; i < 9; ++i) e += (row0 >= off9[i]) ? 1 : 0;

    int n0 = blockIdx.x * 128;                      // N=1024, exact
    const unsigned short* Bd = WdT + (size_t)e * H_ * D_;

    int tid = threadIdx.x;
    int wave = tid >> 6, lane = tid & 63;
    int wm = wave >> 1, wn = wave & 1;
    int ml = lane & 15, q = lane >> 4;
    int sw = ((q + (ml >> 1)) & 3) * 8;

    f32x4 acc[4][4];
#pragma unroll
    for (int i = 0; i < 4; ++i)
#pragma unroll
        for (int j = 0; j < 4; ++j) acc[i][j] = (f32x4)0.f;

    const unsigned short* gsrc[4];
    unsigned short* lbase[4];
#pragma unroll
    for (int i = 0; i < 4; ++i) {
        int qq = wave * 4 + i;
        int buf = qq >> 3, s = qq & 7;
        int r = s * 16 + (lane >> 2);
        int c = ((lane & 3) - (r >> 1)) & 3;
        lbase[i] = &lds[0][buf][s * 512];
        gsrc[i] = (buf == 0)
            ? Hd + (size_t)(row0 + r) * D_ + c * 8
            : Bd + (size_t)(n0 + r) * D_ + c * 8;
    }

    auto issue = [&](int k0, int set) {
#pragma unroll
        for (int i = 0; i < 4; ++i)
            gload_lds16(gsrc[i] + k0, lbase[i] + set * 8192);
    };
    auto compute = [&](int set) {
        const unsigned short* S = &lds[set][0][0];
        s16x8 af[4], bf[4];
#pragma unroll
        for (int i = 0; i < 4; ++i) {
            int R = wm * 64 + i * 16 + ml;
            af[i] = *(const s16x8*)(S + R * 32 + sw);
        }
#pragma unroll
        for (int j = 0; j < 4; ++j) {
            int R = wn * 64 + j * 16 + ml;
            bf[j] = *(const s16x8*)(S + 4096 + R * 32 + sw);
        }
#pragma unroll
        for (int i = 0; i < 4; ++i)
#pragma unroll
            for (int j = 0; j < 4; ++j)
                acc[i][j] = __builtin_amdgcn_mfma_f32_16x16x32_bf16(af[i], bf[j], acc[i][j], 0, 0, 0);
    };

    issue(0, 0);
    for (int k0 = 0; k0 < D_; k0 += 64) {           // D_=2752 = 43*64
        __syncthreads();
        issue(k0 + 32, 1);
        compute(0);
        __syncthreads();
        if (k0 + 64 < D_) issue(k0 + 64, 0);
        compute(1);
    }

    int mbase = row0 + wm * 64;
    int nbase = n0 + wn * 64;
#pragma unroll
    for (int i = 0; i < 4; ++i)
#pragma unroll
        for (int r = 0; r < 4; ++r) {
            int m = mbase + i * 16 + q * 4 + r;
#pragma unroll
            for (int j = 0; j < 4; ++j) {
                int n = nbase + j * 16 + ml;
                eo[(size_t)m * H_ + n] = __float2bfloat16(acc[i][j][r]);
            }
        }
}

// ---------------- combine: out[t] = w0*eo[r0] + w1*eo[r1] + eo[rshared] ----------------
__global__ void k_combine(const unsigned short* __restrict__ eo, const int* __restrict__ tok2row,
                          const int* __restrict__ off, const float* __restrict__ topk_w,
                          float* __restrict__ out) {
    int t = blockIdx.x;
    int j = threadIdx.x * 8;                  // H = 128*8
    int r0 = tok2row[2 * t], r1 = tok2row[2 * t + 1];
    int rs = off[E_] + t;
    float w0 = topk_w[2 * t], w1 = topk_w[2 * t + 1];
    s16x8 a = *(const s16x8*)(eo + (size_t)r0 * H_ + j);
    s16x8 b = *(const s16x8*)(eo + (size_t)r1 * H_ + j);
    s16x8 c = *(const s16x8*)(eo + (size_t)rs * H_ + j);
    float o[8];
#pragma unroll
    for (int i = 0; i < 8; ++i)
        o[i] = w0 * bf2f(a[i]) + w1 * bf2f(b[i]) + bf2f(c[i]);
    float* dst = out + (size_t)t * H_ + j;
    *(float4*)(dst)     = make_float4(o[0], o[1], o[2], o[3]);
    *(float4*)(dst + 4) = make_float4(o[4], o[5], o[6], o[7]);
}

// ---------------- launch ----------------
extern "C" void kernel_launch(void* const* d_in, const int* in_sizes, int n_in,
                              void* d_out, int out_size, void* d_ws, size_t ws_size,
                              hipStream_t stream) {
    const float* x       = (const float*)d_in[0];
    const float* gw      = (const float*)d_in[1];
    const float* we_gate = (const float*)d_in[2];
    const float* we_up   = (const float*)d_in[3];
    const float* we_down = (const float*)d_in[4];
    const float* sw_gate = (const float*)d_in[5];
    const float* sw_up   = (const float*)d_in[6];
    const float* sw_down = (const float*)d_in[7];

    char* ws = (char*)d_ws;
    size_t o = 0;
    auto alloc = [&](size_t b) -> void* {
        void* p = ws + o;
        o += (b + 255) & ~(size_t)255;
        return p;
    };
    int*   count   = (int*)alloc(E_ * 4);
    int*   count2  = (int*)alloc(E_ * 4);
    int*   off     = (int*)alloc(16 * 4);
    int*   topk_e  = (int*)alloc(2 * T_ * 4);
    float* topk_w  = (float*)alloc(2 * T_ * 4);
    int*   perm    = (int*)alloc(MMAX_ * 4);
    float* wrow    = (float*)alloc(MMAX_ * 4);
    int*   tok2row = (int*)alloc(2 * T_ * 4);
    __hip_bfloat16* Xg  = (__hip_bfloat16*)alloc((size_t)MMAX_ * H_ * 2);
    __hip_bfloat16* WgT = (__hip_bfloat16*)alloc((size_t)(E_ + 1) * D_ * H_ * 2);
    __hip_bfloat16* WuT = (__hip_bfloat16*)alloc((size_t)(E_ + 1) * D_ * H_ * 2);
    __hip_bfloat16* WdT = (__hip_bfloat16*)alloc((size_t)(E_ + 1) * H_ * D_ * 2);
    __hip_bfloat16* hidden = (__hip_bfloat16*)alloc((size_t)MMAX_ * D_ * 2);
    // eo (bf16, 29 MB) aliases WgT (50 MB), dead after GEMM1
    __hip_bfloat16* eo = WgT;

    // routing
    k_init<<<(MMAX_ + 255) / 256, 256, 0, stream>>>(count, perm, wrow);
    k_gate<<<T_, 64, 0, stream>>>(x, gw, topk_e, topk_w, count);
    k_scan<<<1, 64, 0, stream>>>(count, off, count2);
    k_scatter<<<(3 * T_ + 255) / 256, 256, 0, stream>>>(topk_e, topk_w, off, count2,
                                                        perm, wrow, tok2row);
    k_gather<<<MMAX_, 128, 0, stream>>>(x, perm, wrow, Xg);

    // weight transpose+convert: experts in slots 0..7, shared in slot 8
    size_t msz = (size_t)D_ * H_;
    k_transpose<<<dim3(D_ / 64, H_ / 64, E_), 256, 0, stream>>>(we_gate, WgT, H_, D_);
    k_transpose<<<dim3(D_ / 64, H_ / 64, 1), 256, 0, stream>>>(sw_gate, WgT + E_ * msz, H_, D_);
    k_transpose<<<dim3(D_ / 64, H_ / 64, E_), 256, 0, stream>>>(we_up, WuT, H_, D_);
    k_transpose<<<dim3(D_ / 64, H_ / 64, 1), 256, 0, stream>>>(sw_up, WuT + E_ * msz, H_, D_);
    k_transpose<<<dim3(H_ / 64, D_ / 64, E_), 256, 0, stream>>>(we_down, WdT, D_, H_);
    k_transpose<<<dim3(H_ / 64, D_ / 64, 1), 256, 0, stream>>>(sw_down, WdT + E_ * msz, D_, H_);

    // GEMM1: fused gate+up+silu -> hidden (bf16), deep-pipelined
    k_gemm1<<<dim3((D_ + 127) / 128, MT256_), 512, 0, stream>>>(
        (const unsigned short*)Xg, (const unsigned short*)WgT, (const unsigned short*)WuT,
        hidden, off);

    // GEMM2: down-proj -> eo rows (bf16, unweighted)
    k_gemm2<<<dim3(H_ / 128, MT128_), 256, 0, stream>>>(
        (const unsigned short*)hidden, (const unsigned short*)WdT, off, eo);

    // combine: weighted sum of the token's 3 rows
    k_combine<<<T_, 128, 0, stream>>>((const unsigned short*)eo, tok2row, off, topk_w,
                                      (float*)d_out);
}

// Round 3
// 735.884 us; speedup vs baseline: 1.0689x; 1.0652x over previous
//
#include <hip/hip_runtime.h>
#include <hip/hip_bf16.h>
#include <math.h>

#define H_ 1024
#define D_ 2752
#define E_ 8
#define T_ 4096
#define MMAX_ 14336   /* max padded rows: 8 segs 256-aligned + 4096 shared */
#define MTY_ 56       /* m-tiles (BM=256) */

typedef __attribute__((ext_vector_type(8))) short s16x8;   // 8 bf16 in 4 VGPRs
typedef __attribute__((ext_vector_type(4))) float f32x4;

// async global->LDS, 16B per lane, LDS dest = wave-uniform base + lane*16
typedef __attribute__((address_space(3))) unsigned int lds_u32;
typedef const __attribute__((address_space(1))) unsigned int gbl_u32;
__device__ __forceinline__ void gload_lds16(const void* g, void* l) {
    __builtin_amdgcn_global_load_lds((gbl_u32*)g, (lds_u32*)l, 16, 0, 0);
}

__device__ __forceinline__ float bf2f(short us) {
    unsigned int u = ((unsigned int)(unsigned short)us) << 16;
    return __uint_as_float(u);
}

// ---------------- init: zero counters / row metadata ----------------
__global__ void k_init(int* __restrict__ count, int* __restrict__ perm,
                       float* __restrict__ wrow) {
    int i = blockIdx.x * 256 + threadIdx.x;
    if (i < E_) count[i] = 0;
    if (i < MMAX_) { perm[i] = 0; wrow[i] = 0.f; }
}

// ---------------- gate: fp32-exact logits, top-2, renormed weights ----------------
__global__ void k_gate(const float* __restrict__ x, const float* __restrict__ gw,
                       int* __restrict__ topk_e, float* __restrict__ topk_w,
                       int* __restrict__ count) {
    int t = blockIdx.x;
    int lane = threadIdx.x;   // 64 threads
    const float* xrow = x + (size_t)t * H_;
    float xr[16];
#pragma unroll
    for (int i = 0; i < 16; ++i) xr[i] = xrow[lane + i * 64];
    float lg[E_];
#pragma unroll
    for (int e = 0; e < E_; ++e) {
        const float* g = gw + (size_t)e * H_;
        float s = 0.f;
#pragma unroll
        for (int i = 0; i < 16; ++i) s += xr[i] * g[lane + i * 64];
        for (int o = 32; o > 0; o >>= 1) s += __shfl_down(s, o, 64);
        lg[e] = s;   // valid on lane 0
    }
    if (lane == 0) {
        int e0 = 0; float l0 = lg[0];
#pragma unroll
        for (int e = 1; e < E_; ++e) if (lg[e] > l0) { l0 = lg[e]; e0 = e; }
        int e1 = -1; float l1 = -1e30f;
#pragma unroll
        for (int e = 0; e < E_; ++e) if (e != e0 && lg[e] > l1) { l1 = lg[e]; e1 = e; }
        float w0 = 1.f / (1.f + expf(l1 - l0));   // softmax denom cancels in renorm
        float w1 = 1.f - w0;
        topk_e[2 * t] = e0; topk_e[2 * t + 1] = e1;
        topk_w[2 * t] = w0; topk_w[2 * t + 1] = w1;
        atomicAdd(&count[e0], 1);
        atomicAdd(&count[e1], 1);
    }
}

// ---------------- scan: 256-aligned segment offsets ----------------
__global__ void k_scan(const int* __restrict__ count, int* __restrict__ off,
                       int* __restrict__ count2) {
    if (threadIdx.x == 0) {
        int o = 0; off[0] = 0;
        for (int e = 0; e < E_; ++e) { o += (count[e] + 255) & ~255; off[e + 1] = o; }
    }
    if (threadIdx.x < E_) count2[threadIdx.x] = 0;
}

// ---------------- scatter: token -> row; also record token's row ids ----------------
__global__ void k_scatter(const int* __restrict__ topk_e, const float* __restrict__ topk_w,
                          const int* __restrict__ off, int* __restrict__ count2,
                          int* __restrict__ perm, float* __restrict__ wrow,
                          int* __restrict__ tok2row) {
    int i = blockIdx.x * 256 + threadIdx.x;
    if (i < 2 * T_) {
        int e = topk_e[i];
        int pos = atomicAdd(&count2[e], 1);
        int r = off[e] + pos;
        perm[r] = i >> 1;
        wrow[r] = topk_w[i];
        tok2row[i] = r;
    } else if (i < 3 * T_) {
        int t = i - 2 * T_;
        int r = off[E_] + t;     // shared-expert segment
        perm[r] = t;
        wrow[r] = 1.f;
    }
}

// ---------------- gather: build Xg rows (bf16), zeros for pad rows ----------------
__global__ void k_gather(const float* __restrict__ x, const int* __restrict__ perm,
                         const float* __restrict__ wrow, __hip_bfloat16* __restrict__ Xg) {
    int r = blockIdx.x;
    int j = threadIdx.x;              // 128 threads, 8 elems each
    int t = perm[r];
    bool act = (wrow[r] != 0.f);
    const float* src = x + (size_t)t * H_;
    __hip_bfloat16* dst = Xg + (size_t)r * H_;
    int h = j * 8;
    float v[8];
#pragma unroll
    for (int i = 0; i < 8; ++i) v[i] = 0.f;
    if (act) {
        float4 a = *(const float4*)(src + h);
        float4 b = *(const float4*)(src + h + 4);
        v[0] = a.x; v[1] = a.y; v[2] = a.z; v[3] = a.w;
        v[4] = b.x; v[5] = b.y; v[6] = b.z; v[7] = b.w;
    }
    __hip_bfloat16 tmp[8];
#pragma unroll
    for (int i = 0; i < 8; ++i) tmp[i] = __float2bfloat16(v[i]);
    *(s16x8*)(dst + h) = *(const s16x8*)tmp;
}

// ---------------- transpose+convert: fp32 [R][C] -> bf16 [C][R], 64x64 tiles ----------------
__global__ void k_transpose(const float* __restrict__ src_, __hip_bfloat16* __restrict__ dst_,
                            int R, int C) {
    const float* src = src_ + (size_t)blockIdx.z * R * C;
    __hip_bfloat16* dst = dst_ + (size_t)blockIdx.z * R * C;
    __shared__ __hip_bfloat16 tile[64][68];   // 68: 8B-aligned rows, conflict break
    int c0 = blockIdx.x * 64, r0 = blockIdx.y * 64;
    int tid = threadIdx.x;                     // 256
    int rsub = tid >> 4;                       // 0..15
    int csub = (tid & 15) * 4;                 // 0..60
#pragma unroll
    for (int i = 0; i < 4; ++i) {
        int r = rsub + i * 16;
        float4 v = *(const float4*)(src + (size_t)(r0 + r) * C + c0 + csub);
        tile[csub + 0][r] = __float2bfloat16(v.x);
        tile[csub + 1][r] = __float2bfloat16(v.y);
        tile[csub + 2][r] = __float2bfloat16(v.z);
        tile[csub + 3][r] = __float2bfloat16(v.w);
    }
    __syncthreads();
    int cs2 = tid >> 4;
    int rs2 = (tid & 15) * 4;
#pragma unroll
    for (int i = 0; i < 4; ++i) {
        int cc = cs2 + i * 16;
        short4 o = *(const short4*)&tile[cc][rs2];
        *(short4*)((unsigned short*)dst + (size_t)(c0 + cc) * R + r0 + rs2) = o;
    }
}

// ================= 8-phase 256-tile GEMMs (m201 template) =================
// K-tile = 64, staged as 4 half-tiles (16KB each): A.k0, B.k0, A.k1, B.k1.
// LDS 128KB: A[2 slots][2 khalf][256 rows x 32 ushort], B likewise at +32768.
// Swizzle within k-half: chunk pos = (c + (row>>1)) & 3  (R1/R2-proven, 0 conflicts).
// Per phase: {ds_read frags, stage 1 half-tile, vmcnt(4), barrier, 16 MFMA, barrier}.
// Retirement check: at phase p's vmcnt(4), the newest 2 half-tiles stay pending;
// every half needed by p was staged >=3 phases earlier -> retired. Tail K-tile
// uses vmcnt(0) at its phase-1 (epilogue drain allowed).

#define WAIT_VM4  asm volatile("s_waitcnt vmcnt(4)" ::: "memory")
#define WAIT_VM0  asm volatile("s_waitcnt vmcnt(0)" ::: "memory")
#define BARRIER   __builtin_amdgcn_s_barrier()
#define SCHEDBAR  __builtin_amdgcn_sched_barrier(0)

// ---------------- GEMM1: hidden = silu(Xg*WgT^T) * (Xg*WuT^T), bf16 out ----------------
// B-hat = [Bg;Bu] interleaved in 16-row groups so each wave owns matching g/u cols.
__global__ __launch_bounds__(512, 2) void k_gemm1(
    const unsigned short* __restrict__ Xg,
    const unsigned short* __restrict__ WgT,
    const unsigned short* __restrict__ WuT,
    __hip_bfloat16* __restrict__ hidden,
    const int* __restrict__ off) {
    __shared__ unsigned short lds[65536];   // 128 KiB

    int row0 = blockIdx.y * 256;
    int off9[9];
#pragma unroll
    for (int i = 0; i < 9; ++i) off9[i] = off[i];
    int Mtot = off9[8] + T_;
    if (row0 >= Mtot) return;
    int e = 0;
#pragma unroll
    for (int i = 1; i < 9; ++i) e += (row0 >= off9[i]) ? 1 : 0;

    int n0 = blockIdx.x * 128;
    size_t wbase = (size_t)e * D_ * H_;
    const unsigned short* Bg = WgT + wbase;
    const unsigned short* Bu = WuT + wbase;

    int tid = threadIdx.x;
    int wave = tid >> 6, lane = tid & 63;
    int wm = wave >> 2, wn = wave & 3;        // 2m x 4n, per-wave out 128 x (32g+32u)
    int ml = lane & 15, q = lane >> 4;
    int sw = ((q + (ml >> 1)) & 3) * 8;       // read-side swizzle within k-half

    f32x4 acc[8][4];
#pragma unroll
    for (int i = 0; i < 8; ++i)
#pragma unroll
        for (int j = 0; j < 4; ++j) acc[i][j] = (f32x4)0.f;

    // staging: 16 issues per half-tile (1KB each); wave w -> issues 2w,2w+1
    const unsigned short* srcA[2];
    const unsigned short* srcB[2];
    int ioff[2];
#pragma unroll
    for (int i1 = 0; i1 < 2; ++i1) {
        int s = 2 * wave + i1;
        int row = s * 16 + (lane >> 2);
        int pos = lane & 3;
        int c = (pos - (row >> 1)) & 3;       // pre-swizzled source chunk
        ioff[i1] = s * 512;
        srcA[i1] = Xg + (size_t)(row0 + row) * H_ + c * 8;
        int bq = row >> 5, bs = row & 31;     // B-hat interleave: 16 g rows / 16 u rows
        const unsigned short* mat = (bs & 16) ? Bu : Bg;
        int ncol = n0 + bq * 16 + (bs & 15);
        if (ncol > D_ - 1) ncol = D_ - 1;     // dup tail, masked in epilogue
        srcB[i1] = mat + (size_t)ncol * H_ + c * 8;
    }

#define G1_STAGE_A(kt, kh)                                                      \
    do { unsigned short* b_ = &lds[((kt) & 1) * 16384 + (kh) * 8192];           \
        gload_lds16(srcA[0] + (kt) * 64 + (kh) * 32, b_ + ioff[0]);             \
        gload_lds16(srcA[1] + (kt) * 64 + (kh) * 32, b_ + ioff[1]); } while (0)
#define G1_STAGE_B(kt, kh)                                                      \
    do { unsigned short* b_ = &lds[32768 + ((kt) & 1) * 16384 + (kh) * 8192];   \
        gload_lds16(srcB[0] + (kt) * 64 + (kh) * 32, b_ + ioff[0]);             \
        gload_lds16(srcB[1] + (kt) * 64 + (kh) * 32, b_ + ioff[1]); } while (0)

    s16x8 af[8], bf[4];
#define G1_LOAD_A(kt, kk)                                                       \
    do { const unsigned short* S_ = &lds[((kt) & 1) * 16384 + (kk) * 8192];     \
        _Pragma("unroll")                                                       \
        for (int i_ = 0; i_ < 8; ++i_)                                          \
            af[i_] = *(const s16x8*)(S_ + (wm * 128 + i_ * 16 + ml) * 32 + sw); } while (0)
#define G1_LOAD_B(kt, kk, b)                                                    \
    do { const unsigned short* S_ = &lds[32768 + ((kt) & 1) * 16384 + (kk) * 8192]; \
        bf[2*(b)]   = *(const s16x8*)(S_ + (wn * 64 + (2*(b)) * 16 + ml) * 32 + sw);   \
        bf[2*(b)+1] = *(const s16x8*)(S_ + (wn * 64 + (2*(b)+1) * 16 + ml) * 32 + sw); } while (0)
#define G1_MM(b)                                                                \
    do { __builtin_amdgcn_s_setprio(1);                                         \
        _Pragma("unroll")                                                       \
        for (int i_ = 0; i_ < 8; ++i_) {                                        \
            acc[i_][2*(b)]   = __builtin_amdgcn_mfma_f32_16x16x32_bf16(af[i_], bf[2*(b)],   acc[i_][2*(b)],   0, 0, 0); \
            acc[i_][2*(b)+1] = __builtin_amdgcn_mfma_f32_16x16x32_bf16(af[i_], bf[2*(b)+1], acc[i_][2*(b)+1], 0, 0, 0); \
        }                                                                       \
        __builtin_amdgcn_s_setprio(0); } while (0)

    const int NKT = H_ / 64;   // 16 K-tiles
    // prologue: stage K-tile 0 fully; wait until A.k0,B.k0 landed
    G1_STAGE_A(0, 0); G1_STAGE_B(0, 0); G1_STAGE_A(0, 1); G1_STAGE_B(0, 1);
    WAIT_VM4; BARRIER; SCHEDBAR;

    for (int kt = 0; kt < NKT - 1; ++kt) {
        // phase 0: (kk=0, b=0)
        G1_LOAD_A(kt, 0); G1_LOAD_B(kt, 0, 0);
        G1_STAGE_A(kt + 1, 0);
        WAIT_VM4; BARRIER; SCHEDBAR;
        G1_MM(0);
        BARRIER; SCHEDBAR;
        // phase 1: (kk=0, b=1)
        G1_LOAD_B(kt, 0, 1);
        G1_STAGE_B(kt + 1, 0);
        WAIT_VM4; BARRIER; SCHEDBAR;
        G1_MM(1);
        BARRIER; SCHEDBAR;
        // phase 2: (kk=1, b=0)
        G1_LOAD_A(kt, 1); G1_LOAD_B(kt, 1, 0);
        G1_STAGE_A(kt + 1, 1);
        WAIT_VM4; BARRIER; SCHEDBAR;
        G1_MM(0);
        BARRIER; SCHEDBAR;
        // phase 3: (kk=1, b=1)
        G1_LOAD_B(kt, 1, 1);
        G1_STAGE_B(kt + 1, 1);
        WAIT_VM4; BARRIER; SCHEDBAR;
        G1_MM(1);
        BARRIER; SCHEDBAR;
    }
    {   // tail K-tile (no stages; drain at phase 1 so kk=1 halves are landed)
        const int kt = NKT - 1;
        G1_LOAD_A(kt, 0); G1_LOAD_B(kt, 0, 0);
        WAIT_VM4; BARRIER; SCHEDBAR;
        G1_MM(0);
        BARRIER; SCHEDBAR;
        G1_LOAD_B(kt, 0, 1);
        WAIT_VM0; BARRIER; SCHEDBAR;
        G1_MM(1);
        G1_LOAD_A(kt, 1); G1_LOAD_B(kt, 1, 0);
        G1_MM(0);
        G1_LOAD_B(kt, 1, 1);
        G1_MM(1);
    }

    // epilogue: in-wave silu(g)*u; C/D layout col=lane&15, row=(lane>>4)*4+reg
    int mbase = row0 + wm * 128;
#pragma unroll
    for (int i = 0; i < 8; ++i)
#pragma unroll
        for (int j2 = 0; j2 < 2; ++j2) {
            int n = n0 + wn * 32 + j2 * 16 + ml;
            if (n < D_) {
#pragma unroll
                for (int r = 0; r < 4; ++r) {
                    int m = mbase + i * 16 + q * 4 + r;
                    float g = acc[i][2 * j2][r], u = acc[i][2 * j2 + 1][r];
                    float hv = (g / (1.f + __expf(-g))) * u;   // silu(g)*u
                    hidden[(size_t)m * D_ + n] = __float2bfloat16(hv);
                }
            }
        }
}

// ---------------- GEMM2: eo[r] = hidden[r] * WdT^T  (bf16 out, unweighted) ----------------
__global__ __launch_bounds__(512, 2) void k_gemm2(
    const unsigned short* __restrict__ Hd,
    const unsigned short* __restrict__ WdT,
    const int* __restrict__ off,
    __hip_bfloat16* __restrict__ eo) {
    __shared__ unsigned short lds[65536];   // 128 KiB

    int row0 = blockIdx.y * 256;
    int off9[9];
#pragma unroll
    for (int i = 0; i < 9; ++i) off9[i] = off[i];
    int Mtot = off9[8] + T_;
    if (row0 >= Mtot) return;
    int e = 0;
#pragma unroll
    for (int i = 1; i < 9; ++i) e += (row0 >= off9[i]) ? 1 : 0;

    int n0 = blockIdx.x * 256;                // N=1024, 4 exact tiles
    const unsigned short* Bd = WdT + (size_t)e * H_ * D_;

    int tid = threadIdx.x;
    int wave = tid >> 6, lane = tid & 63;
    int wm = wave >> 2, wn = wave & 3;        // 2m x 4n, per-wave out 128x64
    int ml = lane & 15, q = lane >> 4;
    int sw = ((q + (ml >> 1)) & 3) * 8;

    f32x4 acc[8][4];
#pragma unroll
    for (int i = 0; i < 8; ++i)
#pragma unroll
        for (int j = 0; j < 4; ++j) acc[i][j] = (f32x4)0.f;

    const unsigned short* srcA[2];
    const unsigned short* srcB[2];
    int ioff[2];
#pragma unroll
    for (int i1 = 0; i1 < 2; ++i1) {
        int s = 2 * wave + i1;
        int row = s * 16 + (lane >> 2);
        int pos = lane & 3;
        int c = (pos - (row >> 1)) & 3;
        ioff[i1] = s * 512;
        srcA[i1] = Hd + (size_t)(row0 + row) * D_ + c * 8;
        srcB[i1] = Bd + (size_t)(n0 + row) * D_ + c * 8;
    }

#define G2_STAGE_A(kt, kh)                                                      \
    do { unsigned short* b_ = &lds[((kt) & 1) * 16384 + (kh) * 8192];           \
        gload_lds16(srcA[0] + (kt) * 64 + (kh) * 32, b_ + ioff[0]);             \
        gload_lds16(srcA[1] + (kt) * 64 + (kh) * 32, b_ + ioff[1]); } while (0)
#define G2_STAGE_B(kt, kh)                                                      \
    do { unsigned short* b_ = &lds[32768 + ((kt) & 1) * 16384 + (kh) * 8192];   \
        gload_lds16(srcB[0] + (kt) * 64 + (kh) * 32, b_ + ioff[0]);             \
        gload_lds16(srcB[1] + (kt) * 64 + (kh) * 32, b_ + ioff[1]); } while (0)

    s16x8 af[8], bf[4];
#define G2_LOAD_A(kt, kk)                                                       \
    do { const unsigned short* S_ = &lds[((kt) & 1) * 16384 + (kk) * 8192];     \
        _Pragma("unroll")                                                       \
        for (int i_ = 0; i_ < 8; ++i_)                                          \
            af[i_] = *(const s16x8*)(S_ + (wm * 128 + i_ * 16 + ml) * 32 + sw); } while (0)
#define G2_LOAD_B(kt, kk, b)                                                    \
    do { const unsigned short* S_ = &lds[32768 + ((kt) & 1) * 16384 + (kk) * 8192]; \
        bf[2*(b)]   = *(const s16x8*)(S_ + (wn * 64 + (2*(b)) * 16 + ml) * 32 + sw);   \
        bf[2*(b)+1] = *(const s16x8*)(S_ + (wn * 64 + (2*(b)+1) * 16 + ml) * 32 + sw); } while (0)
#define G2_MM(b)                                                                \
    do { __builtin_amdgcn_s_setprio(1);                                         \
        _Pragma("unroll")                                                       \
        for (int i_ = 0; i_ < 8; ++i_) {                                        \
            acc[i_][2*(b)]   = __builtin_amdgcn_mfma_f32_16x16x32_bf16(af[i_], bf[2*(b)],   acc[i_][2*(b)],   0, 0, 0); \
            acc[i_][2*(b)+1] = __builtin_amdgcn_mfma_f32_16x16x32_bf16(af[i_], bf[2*(b)+1], acc[i_][2*(b)+1], 0, 0, 0); \
        }                                                                       \
        __builtin_amdgcn_s_setprio(0); } while (0)

    const int NKT = D_ / 64;   // 43 K-tiles
    G2_STAGE_A(0, 0); G2_STAGE_B(0, 0); G2_STAGE_A(0, 1); G2_STAGE_B(0, 1);
    WAIT_VM4; BARRIER; SCHEDBAR;

    for (int kt = 0; kt < NKT - 1; ++kt) {
        G2_LOAD_A(kt, 0); G2_LOAD_B(kt, 0, 0);
        G2_STAGE_A(kt + 1, 0);
        WAIT_VM4; BARRIER; SCHEDBAR;
        G2_MM(0);
        BARRIER; SCHEDBAR;
        G2_LOAD_B(kt, 0, 1);
        G2_STAGE_B(kt + 1, 0);
        WAIT_VM4; BARRIER; SCHEDBAR;
        G2_MM(1);
        BARRIER; SCHEDBAR;
        G2_LOAD_A(kt, 1); G2_LOAD_B(kt, 1, 0);
        G2_STAGE_A(kt + 1, 1);
        WAIT_VM4; BARRIER; SCHEDBAR;
        G2_MM(0);
        BARRIER; SCHEDBAR;
        G2_LOAD_B(kt, 1, 1);
        G2_STAGE_B(kt + 1, 1);
        WAIT_VM4; BARRIER; SCHEDBAR;
        G2_MM(1);
        BARRIER; SCHEDBAR;
    }
    {   // tail K-tile
        const int kt = NKT - 1;
        G2_LOAD_A(kt, 0); G2_LOAD_B(kt, 0, 0);
        WAIT_VM4; BARRIER; SCHEDBAR;
        G2_MM(0);
        BARRIER; SCHEDBAR;
        G2_LOAD_B(kt, 0, 1);
        WAIT_VM0; BARRIER; SCHEDBAR;
        G2_MM(1);
        G2_LOAD_A(kt, 1); G2_LOAD_B(kt, 1, 0);
        G2_MM(0);
        G2_LOAD_B(kt, 1, 1);
        G2_MM(1);
    }

    int mbase = row0 + wm * 128;
    int nbase = n0 + wn * 64;
#pragma unroll
    for (int i = 0; i < 8; ++i)
#pragma unroll
        for (int r = 0; r < 4; ++r) {
            int m = mbase + i * 16 + q * 4 + r;
#pragma unroll
            for (int j = 0; j < 4; ++j) {
                int n = nbase + j * 16 + ml;
                eo[(size_t)m * H_ + n] = __float2bfloat16(acc[i][j][r]);
            }
        }
}

// ---------------- combine: out[t] = w0*eo[r0] + w1*eo[r1] + eo[rshared] ----------------
__global__ void k_combine(const unsigned short* __restrict__ eo, const int* __restrict__ tok2row,
                          const int* __restrict__ off, const float* __restrict__ topk_w,
                          float* __restrict__ out) {
    int t = blockIdx.x;
    int j = threadIdx.x * 8;                  // H = 128*8
    int r0 = tok2row[2 * t], r1 = tok2row[2 * t + 1];
    int rs = off[E_] + t;
    float w0 = topk_w[2 * t], w1 = topk_w[2 * t + 1];
    s16x8 a = *(const s16x8*)(eo + (size_t)r0 * H_ + j);
    s16x8 b = *(const s16x8*)(eo + (size_t)r1 * H_ + j);
    s16x8 c = *(const s16x8*)(eo + (size_t)rs * H_ + j);
    float o[8];
#pragma unroll
    for (int i = 0; i < 8; ++i)
        o[i] = w0 * bf2f(a[i]) + w1 * bf2f(b[i]) + bf2f(c[i]);
    float* dst = out + (size_t)t * H_ + j;
    *(float4*)(dst)     = make_float4(o[0], o[1], o[2], o[3]);
    *(float4*)(dst + 4) = make_float4(o[4], o[5], o[6], o[7]);
}

// ---------------- launch ----------------
extern "C" void kernel_launch(void* const* d_in, const int* in_sizes, int n_in,
                              void* d_out, int out_size, void* d_ws, size_t ws_size,
                              hipStream_t stream) {
    const float* x       = (const float*)d_in[0];
    const float* gw      = (const float*)d_in[1];
    const float* we_gate = (const float*)d_in[2];
    const float* we_up   = (const float*)d_in[3];
    const float* we_down = (const float*)d_in[4];
    const float* sw_gate = (const float*)d_in[5];
    const float* sw_up   = (const float*)d_in[6];
    const float* sw_down = (const float*)d_in[7];

    char* ws = (char*)d_ws;
    size_t o = 0;
    auto alloc = [&](size_t b) -> void* {
        void* p = ws + o;
        o += (b + 255) & ~(size_t)255;
        return p;
    };
    int*   count   = (int*)alloc(E_ * 4);
    int*   count2  = (int*)alloc(E_ * 4);
    int*   off     = (int*)alloc(16 * 4);
    int*   topk_e  = (int*)alloc(2 * T_ * 4);
    float* topk_w  = (float*)alloc(2 * T_ * 4);
    int*   perm    = (int*)alloc(MMAX_ * 4);
    float* wrow    = (float*)alloc(MMAX_ * 4);
    int*   tok2row = (int*)alloc(2 * T_ * 4);
    __hip_bfloat16* Xg  = (__hip_bfloat16*)alloc((size_t)MMAX_ * H_ * 2);
    __hip_bfloat16* WgT = (__hip_bfloat16*)alloc((size_t)(E_ + 1) * D_ * H_ * 2);
    __hip_bfloat16* WuT = (__hip_bfloat16*)alloc((size_t)(E_ + 1) * D_ * H_ * 2);
    __hip_bfloat16* WdT = (__hip_bfloat16*)alloc((size_t)(E_ + 1) * H_ * D_ * 2);
    __hip_bfloat16* hidden = (__hip_bfloat16*)alloc((size_t)MMAX_ * D_ * 2);
    // eo (bf16, 29 MB) aliases WgT (50 MB), dead after GEMM1
    __hip_bfloat16* eo = WgT;

    // routing
    k_init<<<(MMAX_ + 255) / 256, 256, 0, stream>>>(count, perm, wrow);
    k_gate<<<T_, 64, 0, stream>>>(x, gw, topk_e, topk_w, count);
    k_scan<<<1, 64, 0, stream>>>(count, off, count2);
    k_scatter<<<(3 * T_ + 255) / 256, 256, 0, stream>>>(topk_e, topk_w, off, count2,
                                                        perm, wrow, tok2row);
    k_gather<<<MMAX_, 128, 0, stream>>>(x, perm, wrow, Xg);

    // weight transpose+convert: experts in slots 0..7, shared in slot 8
    size_t msz = (size_t)D_ * H_;
    k_transpose<<<dim3(D_ / 64, H_ / 64, E_), 256, 0, stream>>>(we_gate, WgT, H_, D_);
    k_transpose<<<dim3(D_ / 64, H_ / 64, 1), 256, 0, stream>>>(sw_gate, WgT + E_ * msz, H_, D_);
    k_transpose<<<dim3(D_ / 64, H_ / 64, E_), 256, 0, stream>>>(we_up, WuT, H_, D_);
    k_transpose<<<dim3(D_ / 64, H_ / 64, 1), 256, 0, stream>>>(sw_up, WuT + E_ * msz, H_, D_);
    k_transpose<<<dim3(H_ / 64, D_ / 64, E_), 256, 0, stream>>>(we_down, WdT, D_, H_);
    k_transpose<<<dim3(H_ / 64, D_ / 64, 1), 256, 0, stream>>>(sw_down, WdT + E_ * msz, D_, H_);

    // GEMM1: fused gate+up+silu -> hidden (bf16), 8-phase schedule
    k_gemm1<<<dim3((D_ + 127) / 128, MTY_), 512, 0, stream>>>(
        (const unsigned short*)Xg, (const unsigned short*)WgT, (const unsigned short*)WuT,
        hidden, off);

    // GEMM2: down-proj -> eo rows (bf16, unweighted), 8-phase schedule
    k_gemm2<<<dim3(H_ / 256, MTY_), 512, 0, stream>>>(
        (const unsigned short*)hidden, (const unsigned short*)WdT, off, eo);

    // combine: weighted sum of the token's 3 rows
    k_combine<<<T_, 128, 0, stream>>>((const unsigned short*)eo, tok2row, off, topk_w,
                                      (float*)d_out);
}